// Round 15
// baseline (172.624 us; speedup 1.0000x reference)
//
#include <hip/hip_runtime.h>

// Problem constants (B=4, S=2048 -> M=8192; K=4096; N=4096)
#define M_DIM 8192
#define N_DIM 4096
#define K_DIM 4096

typedef __attribute__((ext_vector_type(4))) int i32x4;

__device__ __forceinline__ void gload_lds16(const void* g, void* l) {
  __builtin_amdgcn_global_load_lds(
      (const __attribute__((address_space(1))) void*)g,
      (__attribute__((address_space(3))) void*)l, 16, 0, 0);
}

#define MFMA_I8(a, b, c) __builtin_amdgcn_mfma_i32_16x16x64_i8((a), (b), (c), 0, 0, 0)

// ------- 1) fused prep: per-row int8 quant (blocks 0..8191) +
//            weight transpose/pack int32[K][N] -> int8[N][K] (blocks 8192+)
__global__ __launch_bounds__(256) void prep_fused(const float* __restrict__ x,
                                                  signed char* __restrict__ q,
                                                  float* __restrict__ iscale,
                                                  const int* __restrict__ w,
                                                  signed char* __restrict__ wt) {
  const int t = threadIdx.x;
  if (blockIdx.x < M_DIM) {
    // ---- quant path: one block per row of 4096 floats
    const int row = blockIdx.x;
    const float* xr = x + (size_t)row * K_DIM;
    float4 v[4];
    float vmax = 0.f;
#pragma unroll
    for (int i = 0; i < 4; ++i) {
      v[i] = reinterpret_cast<const float4*>(xr)[t + i * 256];
      vmax = fmaxf(vmax, fmaxf(fmaxf(fabsf(v[i].x), fabsf(v[i].y)),
                               fmaxf(fabsf(v[i].z), fabsf(v[i].w))));
    }
#pragma unroll
    for (int off = 32; off > 0; off >>= 1)
      vmax = fmaxf(vmax, __shfl_xor(vmax, off));
    __shared__ float smax[4];
    if ((t & 63) == 0) smax[t >> 6] = vmax;
    __syncthreads();
    vmax = fmaxf(fmaxf(smax[0], smax[1]), fmaxf(smax[2], smax[3]));
    const float isc = vmax * (1.0f / 127.0f);
    if (t == 0) iscale[row] = isc;
    const float s = fmaxf(isc, 1e-12f);
    unsigned* qrow = reinterpret_cast<unsigned*>(q + (size_t)row * K_DIM);
#pragma unroll
    for (int i = 0; i < 4; ++i) {
      int b0 = (int)rintf(fminf(fmaxf(v[i].x / s, -127.f), 127.f));
      int b1 = (int)rintf(fminf(fmaxf(v[i].y / s, -127.f), 127.f));
      int b2 = (int)rintf(fminf(fmaxf(v[i].z / s, -127.f), 127.f));
      int b3 = (int)rintf(fminf(fmaxf(v[i].w / s, -127.f), 127.f));
      qrow[t + i * 256] = (unsigned)(b0 & 0xff) | ((unsigned)(b1 & 0xff) << 8) |
                          ((unsigned)(b2 & 0xff) << 16) |
                          ((unsigned)(b3 & 0xff) << 24);
    }
  } else {
    // ---- transpose path: 64x64 tile per block
    __shared__ signed char tile[64][68];
    const int lin = blockIdx.x - M_DIM;
    const int n0 = (lin & 63) * 64;
    const int k0 = (lin >> 6) * 64;
#pragma unroll
    for (int i = 0; i < 4; ++i) {
      int idx = t + i * 256;
      int r = idx >> 4;
      int c = idx & 15;
      int4 v = *reinterpret_cast<const int4*>(w + (size_t)(k0 + r) * N_DIM + n0 + c * 4);
      unsigned dw = (unsigned)(v.x & 0xff) | ((unsigned)(v.y & 0xff) << 8) |
                    ((unsigned)(v.z & 0xff) << 16) | ((unsigned)(v.w & 0xff) << 24);
      *reinterpret_cast<unsigned*>(&tile[r][c * 4]) = dw;
    }
    __syncthreads();
#pragma unroll
    for (int i = 0; i < 4; ++i) {
      int idx = t + i * 256;
      int n = idx >> 4;
      int kd = idx & 15;
      unsigned b0 = (unsigned char)tile[kd * 4 + 0][n];
      unsigned b1 = (unsigned char)tile[kd * 4 + 1][n];
      unsigned b2 = (unsigned char)tile[kd * 4 + 2][n];
      unsigned b3 = (unsigned char)tile[kd * 4 + 3][n];
      unsigned dw = b0 | (b1 << 8) | (b2 << 16) | (b3 << 24);
      *reinterpret_cast<unsigned*>(wt + (size_t)(n0 + n) * K_DIM + k0 + kd * 4) = dw;
    }
  }
}

// ---------------- 2) int8 GEMM, 256x256 tile, reduced-sync 3-phase -------
// R12/R14 structure + PEELED LAST K-TILE: kt=31 needs no staging; after a
// full vmcnt(0)+barrier it is barrier-free, and each quadrant's nt-store
// burst issues right after its MFMA cluster -> stores overlap the next
// quadrant's ds_reads/MFMAs instead of being exposed at the end.
#define BM 256
#define BN 256
#define BK 128
#define NKT (K_DIM / BK)

__global__ __launch_bounds__(512, 2) void gemm_i8(
    const signed char* __restrict__ q,   // [M][K]
    const signed char* __restrict__ wt,  // [N][K]
    const float* __restrict__ iscale,    // [M]
    const float* __restrict__ wscale,    // [N]
    const float* __restrict__ bias,      // [N]
    float* __restrict__ out)             // [M][N]
{
  __shared__ __align__(16) signed char lA[2][BM * BK];  // 2 x 32 KB
  __shared__ __align__(16) signed char lB[2][BN * BK];  // 2 x 32 KB

  const int t = threadIdx.x;
  const int l = t & 63;
  const int wid = t >> 6;   // 0..7
  const int wm = wid >> 2;  // 0..1
  const int wn = wid & 3;   // 0..3
  const int fl = l & 15;    // fragment row-in-16
  const int fk = l >> 4;    // 16B k-chunk within K=64
  const int ps0 = fk ^ (fl & 7);        // swizzled slot, ks=0
  const int ps1 = (4 + fk) ^ (fl & 7);  // swizzled slot, ks=1

  // XCD-aware block swizzle (nwg=512, divisible by 8)
  const int lin = blockIdx.y * 16 + blockIdx.x;
  const int swz = (lin & 7) * 64 + (lin >> 3);
  const int m0 = (swz >> 4) * BM;
  const int n0 = (swz & 15) * BN;

  // staging geometry: thread covers one 16B unit per load-round
  const int srow = t >> 3;  // 0..63
  const int ss = t & 7;
  const unsigned gss = (unsigned)((ss ^ (srow & 7)) << 4);  // pre-swizzled
  const int a0r = srow, a1r = 128 + srow, a2r = 64 + srow, a3r = 192 + srow;
  const int blr = ((srow >> 5) << 6) + (srow & 31);
  const int b0r = blr, b1r = 128 + blr, b2r = 32 + blr, b3r = 160 + blr;

  const unsigned goA0 = (unsigned)(m0 + a0r) * K_DIM + gss;
  const unsigned goA1 = (unsigned)(m0 + a1r) * K_DIM + gss;
  const unsigned goA2 = (unsigned)(m0 + a2r) * K_DIM + gss;
  const unsigned goA3 = (unsigned)(m0 + a3r) * K_DIM + gss;
  const unsigned goB0 = (unsigned)(n0 + b0r) * K_DIM + gss;
  const unsigned goB1 = (unsigned)(n0 + b1r) * K_DIM + gss;
  const unsigned goB2 = (unsigned)(n0 + b2r) * K_DIM + gss;
  const unsigned goB3 = (unsigned)(n0 + b3r) * K_DIM + gss;
  const int loA0 = a0r * BK + (ss << 4), loA1 = a1r * BK + (ss << 4);
  const int loA2 = a2r * BK + (ss << 4), loA3 = a3r * BK + (ss << 4);
  const int loB0 = b0r * BK + (ss << 4), loB1 = b1r * BK + (ss << 4);
  const int loB2 = b2r * BK + (ss << 4), loB3 = b3r * BK + (ss << 4);

  i32x4 acc[8][4] = {};        // [mi][ni]; mi>>2 = mhalf, ni>>1 = nhalf
  i32x4 af[4][2], bf0[2][2], bf1[2][2];

  const int colb = n0 + wn * 64 + fl;
  const int rowb = m0 + wm * 128 + fk * 4;

  // quadrant store: mb in {0,4} (mhalf), nb in {0,2} (nhalf), nt stores
#define STORE_QUAD(mb, nb)                                                   \
  {                                                                          \
    _Pragma("unroll") for (int mi = 0; mi < 4; ++mi) {                       \
      const int rowoff = ((mb) ? 64 : 0) + mi * 16;                          \
      float is4[4];                                                          \
      _Pragma("unroll") for (int r = 0; r < 4; ++r) is4[r] =                 \
          iscale[rowb + rowoff + r];                                         \
      _Pragma("unroll") for (int nj = 0; nj < 2; ++nj) {                     \
        const int ni = (nb) + nj;                                            \
        const int col = colb + (ni >> 1) * 32 + (ni & 1) * 16;               \
        const float wsc = wscale[col];                                       \
        const float bs = bias[col];                                          \
        _Pragma("unroll") for (int r = 0; r < 4; ++r) {                      \
          float vout = (float)acc[(mb) + mi][ni][r] * is4[r] * wsc + bs;     \
          __builtin_nontemporal_store(                                       \
              vout, &out[(size_t)(rowb + rowoff + r) * N_DIM + col]);        \
        }                                                                    \
      }                                                                      \
    }                                                                        \
  }

  // ---- prologue: stage tile 0 into buf 0 in steady-state issue order
  gload_lds16(q + goA0, &lA[0][0] + loA0);
  gload_lds16(q + goA1, &lA[0][0] + loA1);
  gload_lds16(wt + goB0, &lB[0][0] + loB0);
  gload_lds16(wt + goB1, &lB[0][0] + loB1);
  gload_lds16(wt + goB2, &lB[0][0] + loB2);
  gload_lds16(wt + goB3, &lB[0][0] + loB3);
  gload_lds16(q + goA2, &lA[0][0] + loA2);
  gload_lds16(q + goA3, &lA[0][0] + loA3);
  asm volatile("s_waitcnt vmcnt(4)" ::: "memory");
  __builtin_amdgcn_s_barrier();

  for (int kt = 0; kt < NKT - 1; ++kt) {
    const int cur = kt & 1;
    const signed char* lAc = &lA[cur][0];
    const signed char* lBc = &lB[cur][0];
    signed char* lAn = &lA[cur ^ 1][0];
    signed char* lBn = &lB[cur ^ 1][0];
    const unsigned kbn = (unsigned)((kt + 1) * BK);

    // ---------- phase 0: read A(mh0)+B(nh0); issue A0,A1; MFMA q(0,0)
#pragma unroll
    for (int mi = 0; mi < 4; ++mi) {
      const int row = wm * 128 + mi * 16 + fl;
      af[mi][0] = *(const i32x4*)(lAc + row * BK + ps0 * 16);
      af[mi][1] = *(const i32x4*)(lAc + row * BK + ps1 * 16);
    }
#pragma unroll
    for (int ni = 0; ni < 2; ++ni) {
      const int row = wn * 64 + ni * 16 + fl;
      bf0[ni][0] = *(const i32x4*)(lBc + row * BK + ps0 * 16);
      bf0[ni][1] = *(const i32x4*)(lBc + row * BK + ps1 * 16);
    }
    gload_lds16(q + (goA0 + kbn), lAn + loA0);
    gload_lds16(q + (goA1 + kbn), lAn + loA1);
    asm volatile("s_waitcnt lgkmcnt(0)" ::: "memory");
    __builtin_amdgcn_sched_barrier(0);
    __builtin_amdgcn_s_setprio(1);
#pragma unroll
    for (int mi = 0; mi < 4; ++mi)
#pragma unroll
      for (int ni = 0; ni < 2; ++ni) {
        acc[mi][ni] = MFMA_I8(af[mi][0], bf0[ni][0], acc[mi][ni]);
        acc[mi][ni] = MFMA_I8(af[mi][1], bf0[ni][1], acc[mi][ni]);
      }
    __builtin_amdgcn_s_setprio(0);
    asm volatile("s_waitcnt vmcnt(2)" ::: "memory");
    __builtin_amdgcn_s_barrier();

    // ---------- phase 1: read B(nh1); issue B0,B1; MFMA q(0,1)
#pragma unroll
    for (int ni = 0; ni < 2; ++ni) {
      const int row = wn * 64 + 32 + ni * 16 + fl;
      bf1[ni][0] = *(const i32x4*)(lBc + row * BK + ps0 * 16);
      bf1[ni][1] = *(const i32x4*)(lBc + row * BK + ps1 * 16);
    }
    gload_lds16(wt + (goB0 + kbn), lBn + loB0);
    gload_lds16(wt + (goB1 + kbn), lBn + loB1);
    asm volatile("s_waitcnt lgkmcnt(0)" ::: "memory");
    __builtin_amdgcn_sched_barrier(0);
    __builtin_amdgcn_s_setprio(1);
#pragma unroll
    for (int mi = 0; mi < 4; ++mi)
#pragma unroll
      for (int ni = 0; ni < 2; ++ni) {
        acc[mi][2 + ni] = MFMA_I8(af[mi][0], bf1[ni][0], acc[mi][2 + ni]);
        acc[mi][2 + ni] = MFMA_I8(af[mi][1], bf1[ni][1], acc[mi][2 + ni]);
      }
    __builtin_amdgcn_s_setprio(0);

    // ---------- phase 2 (merged): read A(mh1); issue B2,B3,A2,A3;
    //            MFMA q(1,1) then q(1,0) as one 32-MFMA cluster
#pragma unroll
    for (int mi = 0; mi < 4; ++mi) {
      const int row = wm * 128 + 64 + mi * 16 + fl;
      af[mi][0] = *(const i32x4*)(lAc + row * BK + ps0 * 16);
      af[mi][1] = *(const i32x4*)(lAc + row * BK + ps1 * 16);
    }
    gload_lds16(wt + (goB2 + kbn), lBn + loB2);
    gload_lds16(wt + (goB3 + kbn), lBn + loB3);
    gload_lds16(q + (goA2 + kbn), lAn + loA2);
    gload_lds16(q + (goA3 + kbn), lAn + loA3);
    asm volatile("s_waitcnt lgkmcnt(0)" ::: "memory");
    __builtin_amdgcn_sched_barrier(0);
    __builtin_amdgcn_s_setprio(1);
#pragma unroll
    for (int mi = 0; mi < 4; ++mi)
#pragma unroll
      for (int ni = 0; ni < 2; ++ni) {
        acc[4 + mi][2 + ni] = MFMA_I8(af[mi][0], bf1[ni][0], acc[4 + mi][2 + ni]);
        acc[4 + mi][2 + ni] = MFMA_I8(af[mi][1], bf1[ni][1], acc[4 + mi][2 + ni]);
      }
#pragma unroll
    for (int mi = 0; mi < 4; ++mi)
#pragma unroll
      for (int ni = 0; ni < 2; ++ni) {
        acc[4 + mi][ni] = MFMA_I8(af[mi][0], bf0[ni][0], acc[4 + mi][ni]);
        acc[4 + mi][ni] = MFMA_I8(af[mi][1], bf0[ni][1], acc[4 + mi][ni]);
      }
    __builtin_amdgcn_s_setprio(0);
    asm volatile("s_waitcnt vmcnt(4)" ::: "memory");
    __builtin_amdgcn_s_barrier();
  }

  // ---- full drain: everything staged & visible; peeled tile is read-only
  asm volatile("s_waitcnt vmcnt(0)" ::: "memory");
  __builtin_amdgcn_s_barrier();

  // ---- peeled last K-tile (buf 1): no staging, no barriers; store each
  //      quadrant right after its MFMA cluster (overlaps next phase)
  {
    const signed char* lAc = &lA[1][0];
    const signed char* lBc = &lB[1][0];

    // ph0: q(0,0)
#pragma unroll
    for (int mi = 0; mi < 4; ++mi) {
      const int row = wm * 128 + mi * 16 + fl;
      af[mi][0] = *(const i32x4*)(lAc + row * BK + ps0 * 16);
      af[mi][1] = *(const i32x4*)(lAc + row * BK + ps1 * 16);
    }
#pragma unroll
    for (int ni = 0; ni < 2; ++ni) {
      const int row = wn * 64 + ni * 16 + fl;
      bf0[ni][0] = *(const i32x4*)(lBc + row * BK + ps0 * 16);
      bf0[ni][1] = *(const i32x4*)(lBc + row * BK + ps1 * 16);
    }
    asm volatile("s_waitcnt lgkmcnt(0)" ::: "memory");
    __builtin_amdgcn_sched_barrier(0);
#pragma unroll
    for (int mi = 0; mi < 4; ++mi)
#pragma unroll
      for (int ni = 0; ni < 2; ++ni) {
        acc[mi][ni] = MFMA_I8(af[mi][0], bf0[ni][0], acc[mi][ni]);
        acc[mi][ni] = MFMA_I8(af[mi][1], bf0[ni][1], acc[mi][ni]);
      }
    STORE_QUAD(0, 0)

    // ph1: q(0,1)
#pragma unroll
    for (int ni = 0; ni < 2; ++ni) {
      const int row = wn * 64 + 32 + ni * 16 + fl;
      bf1[ni][0] = *(const i32x4*)(lBc + row * BK + ps0 * 16);
      bf1[ni][1] = *(const i32x4*)(lBc + row * BK + ps1 * 16);
    }
    asm volatile("s_waitcnt lgkmcnt(0)" ::: "memory");
    __builtin_amdgcn_sched_barrier(0);
#pragma unroll
    for (int mi = 0; mi < 4; ++mi)
#pragma unroll
      for (int ni = 0; ni < 2; ++ni) {
        acc[mi][2 + ni] = MFMA_I8(af[mi][0], bf1[ni][0], acc[mi][2 + ni]);
        acc[mi][2 + ni] = MFMA_I8(af[mi][1], bf1[ni][1], acc[mi][2 + ni]);
      }
    STORE_QUAD(0, 2)

    // ph2: q(1,1) then q(1,0)
#pragma unroll
    for (int mi = 0; mi < 4; ++mi) {
      const int row = wm * 128 + 64 + mi * 16 + fl;
      af[mi][0] = *(const i32x4*)(lAc + row * BK + ps0 * 16);
      af[mi][1] = *(const i32x4*)(lAc + row * BK + ps1 * 16);
    }
    asm volatile("s_waitcnt lgkmcnt(0)" ::: "memory");
    __builtin_amdgcn_sched_barrier(0);
#pragma unroll
    for (int mi = 0; mi < 4; ++mi)
#pragma unroll
      for (int ni = 0; ni < 2; ++ni) {
        acc[4 + mi][2 + ni] = MFMA_I8(af[mi][0], bf1[ni][0], acc[4 + mi][2 + ni]);
        acc[4 + mi][2 + ni] = MFMA_I8(af[mi][1], bf1[ni][1], acc[4 + mi][2 + ni]);
      }
    STORE_QUAD(4, 2)
#pragma unroll
    for (int mi = 0; mi < 4; ++mi)
#pragma unroll
      for (int ni = 0; ni < 2; ++ni) {
        acc[4 + mi][ni] = MFMA_I8(af[mi][0], bf0[ni][0], acc[4 + mi][ni]);
        acc[4 + mi][ni] = MFMA_I8(af[mi][1], bf0[ni][1], acc[4 + mi][ni]);
      }
    STORE_QUAD(4, 0)
  }
#undef STORE_QUAD
}

extern "C" void kernel_launch(void* const* d_in, const int* in_sizes, int n_in,
                              void* d_out, int out_size, void* d_ws, size_t ws_size,
                              hipStream_t stream) {
  const float* inp = (const float*)d_in[0];
  const int* wq32 = (const int*)d_in[1];  // int8 weight delivered as int32 [K][N]
  const float* wscale = (const float*)d_in[2];
  const float* bias = (const float*)d_in[3];
  float* out = (float*)d_out;

  signed char* q = (signed char*)d_ws;
  signed char* wt = q + (size_t)M_DIM * K_DIM;
  float* iscale = (float*)(wt + (size_t)N_DIM * K_DIM);

  // fused quant (8192 blocks) + transpose (4096 blocks) in one launch
  prep_fused<<<M_DIM + (N_DIM / 64) * (K_DIM / 64), 256, 0, stream>>>(
      inp, q, iscale, wq32, wt);
  gemm_i8<<<dim3(N_DIM / BN, M_DIM / BM), 512, 0, stream>>>(q, wt, iscale, wscale,
                                                            bias, out);
}

// Round 16
// 160.671 us; speedup vs baseline: 1.0744x; 1.0744x over previous
//
#include <hip/hip_runtime.h>

// Problem constants (B=4, S=2048 -> M=8192; K=4096; N=4096)
#define M_DIM 8192
#define N_DIM 4096
#define K_DIM 4096

typedef __attribute__((ext_vector_type(4))) int i32x4;
typedef __attribute__((ext_vector_type(4))) float f32x4;

__device__ __forceinline__ void gload_lds16(const void* g, void* l) {
  __builtin_amdgcn_global_load_lds(
      (const __attribute__((address_space(1))) void*)g,
      (__attribute__((address_space(3))) void*)l, 16, 0, 0);
}

#define MFMA_I8(a, b, c) __builtin_amdgcn_mfma_i32_16x16x64_i8((a), (b), (c), 0, 0, 0)

// ------- 1) fused prep: per-row int8 quant (blocks 0..8191) +
//            weight transpose/pack int32[K][N] -> int8[N][K] (blocks 8192+)
__global__ __launch_bounds__(256) void prep_fused(const float* __restrict__ x,
                                                  signed char* __restrict__ q,
                                                  float* __restrict__ iscale,
                                                  const int* __restrict__ w,
                                                  signed char* __restrict__ wt) {
  const int t = threadIdx.x;
  if (blockIdx.x < M_DIM) {
    // ---- quant path: one block per row of 4096 floats
    const int row = blockIdx.x;
    const float* xr = x + (size_t)row * K_DIM;
    float4 v[4];
    float vmax = 0.f;
#pragma unroll
    for (int i = 0; i < 4; ++i) {
      v[i] = reinterpret_cast<const float4*>(xr)[t + i * 256];
      vmax = fmaxf(vmax, fmaxf(fmaxf(fabsf(v[i].x), fabsf(v[i].y)),
                               fmaxf(fabsf(v[i].z), fabsf(v[i].w))));
    }
#pragma unroll
    for (int off = 32; off > 0; off >>= 1)
      vmax = fmaxf(vmax, __shfl_xor(vmax, off));
    __shared__ float smax[4];
    if ((t & 63) == 0) smax[t >> 6] = vmax;
    __syncthreads();
    vmax = fmaxf(fmaxf(smax[0], smax[1]), fmaxf(smax[2], smax[3]));
    const float isc = vmax * (1.0f / 127.0f);
    if (t == 0) iscale[row] = isc;
    const float s = fmaxf(isc, 1e-12f);
    unsigned* qrow = reinterpret_cast<unsigned*>(q + (size_t)row * K_DIM);
#pragma unroll
    for (int i = 0; i < 4; ++i) {
      int b0 = (int)rintf(fminf(fmaxf(v[i].x / s, -127.f), 127.f));
      int b1 = (int)rintf(fminf(fmaxf(v[i].y / s, -127.f), 127.f));
      int b2 = (int)rintf(fminf(fmaxf(v[i].z / s, -127.f), 127.f));
      int b3 = (int)rintf(fminf(fmaxf(v[i].w / s, -127.f), 127.f));
      qrow[t + i * 256] = (unsigned)(b0 & 0xff) | ((unsigned)(b1 & 0xff) << 8) |
                          ((unsigned)(b2 & 0xff) << 16) |
                          ((unsigned)(b3 & 0xff) << 24);
    }
  } else {
    // ---- transpose path: 64x64 tile per block
    __shared__ signed char tile[64][68];
    const int lin = blockIdx.x - M_DIM;
    const int n0 = (lin & 63) * 64;
    const int k0 = (lin >> 6) * 64;
#pragma unroll
    for (int i = 0; i < 4; ++i) {
      int idx = t + i * 256;
      int r = idx >> 4;
      int c = idx & 15;
      int4 v = *reinterpret_cast<const int4*>(w + (size_t)(k0 + r) * N_DIM + n0 + c * 4);
      unsigned dw = (unsigned)(v.x & 0xff) | ((unsigned)(v.y & 0xff) << 8) |
                    ((unsigned)(v.z & 0xff) << 16) | ((unsigned)(v.w & 0xff) << 24);
      *reinterpret_cast<unsigned*>(&tile[r][c * 4]) = dw;
    }
    __syncthreads();
#pragma unroll
    for (int i = 0; i < 4; ++i) {
      int idx = t + i * 256;
      int n = idx >> 4;
      int kd = idx & 15;
      unsigned b0 = (unsigned char)tile[kd * 4 + 0][n];
      unsigned b1 = (unsigned char)tile[kd * 4 + 1][n];
      unsigned b2 = (unsigned char)tile[kd * 4 + 2][n];
      unsigned b3 = (unsigned char)tile[kd * 4 + 3][n];
      unsigned dw = b0 | (b1 << 8) | (b2 << 16) | (b3 << 24);
      *reinterpret_cast<unsigned*>(wt + (size_t)(n0 + n) * K_DIM + k0 + kd * 4) = dw;
    }
  }
}

// ---------------- 2) int8 GEMM, 256x256 tile, reduced-sync 3-phase -------
// R12 main loop (best steady-state) + LDS-transposed nt epilogue:
// dequant acc -> LDS (128x256 f32, 2 passes), read back float4-contiguous,
// nt-store dwordx4 (1KB/wave-instr, full-line HBM writes). Fixes R14/R15's
// write amplification (WRITE_SIZE 170MB vs 134MB ideal from scalar 4B nt
// stores) while keeping nt (output must not evict x from L3 between
// replays -- that's what made prep fast).
#define BM 256
#define BN 256
#define BK 128
#define NKT (K_DIM / BK)
#define BUFSZ (BM * BK)

__global__ __launch_bounds__(512, 2) void gemm_i8(
    const signed char* __restrict__ q,   // [M][K]
    const signed char* __restrict__ wt,  // [N][K]
    const float* __restrict__ iscale,    // [M]
    const float* __restrict__ wscale,    // [N]
    const float* __restrict__ bias,      // [N]
    float* __restrict__ out)             // [M][N]
{
  __shared__ __align__(16) signed char lsmem[4 * BUFSZ];  // 128 KB
#define LAb(buf) (lsmem + (buf) * BUFSZ)
#define LBb(buf) (lsmem + (2 + (buf)) * BUFSZ)

  const int t = threadIdx.x;
  const int l = t & 63;
  const int wid = t >> 6;   // 0..7
  const int wm = wid >> 2;  // 0..1
  const int wn = wid & 3;   // 0..3
  const int fl = l & 15;    // fragment row-in-16
  const int fk = l >> 4;    // 16B k-chunk within K=64
  const int ps0 = fk ^ (fl & 7);        // swizzled slot, ks=0
  const int ps1 = (4 + fk) ^ (fl & 7);  // swizzled slot, ks=1

  // XCD-aware block swizzle (nwg=512, divisible by 8)
  const int lin = blockIdx.y * 16 + blockIdx.x;
  const int swz = (lin & 7) * 64 + (lin >> 3);
  const int m0 = (swz >> 4) * BM;
  const int n0 = (swz & 15) * BN;

  // staging geometry: thread covers one 16B unit per load-round
  const int srow = t >> 3;  // 0..63
  const int ss = t & 7;
  const unsigned gss = (unsigned)((ss ^ (srow & 7)) << 4);  // pre-swizzled
  const int a0r = srow, a1r = 128 + srow, a2r = 64 + srow, a3r = 192 + srow;
  const int blr = ((srow >> 5) << 6) + (srow & 31);
  const int b0r = blr, b1r = 128 + blr, b2r = 32 + blr, b3r = 160 + blr;

  const unsigned goA0 = (unsigned)(m0 + a0r) * K_DIM + gss;
  const unsigned goA1 = (unsigned)(m0 + a1r) * K_DIM + gss;
  const unsigned goA2 = (unsigned)(m0 + a2r) * K_DIM + gss;
  const unsigned goA3 = (unsigned)(m0 + a3r) * K_DIM + gss;
  const unsigned goB0 = (unsigned)(n0 + b0r) * K_DIM + gss;
  const unsigned goB1 = (unsigned)(n0 + b1r) * K_DIM + gss;
  const unsigned goB2 = (unsigned)(n0 + b2r) * K_DIM + gss;
  const unsigned goB3 = (unsigned)(n0 + b3r) * K_DIM + gss;
  const int loA0 = a0r * BK + (ss << 4), loA1 = a1r * BK + (ss << 4);
  const int loA2 = a2r * BK + (ss << 4), loA3 = a3r * BK + (ss << 4);
  const int loB0 = b0r * BK + (ss << 4), loB1 = b1r * BK + (ss << 4);
  const int loB2 = b2r * BK + (ss << 4), loB3 = b3r * BK + (ss << 4);

  i32x4 acc[8][4] = {};        // [mi][ni]; mi>>2 = mhalf, ni>>1 = nhalf
  i32x4 af[4][2], bf0[2][2], bf1[2][2];

  // ---- prologue: stage tile 0 into buf 0 in steady-state issue order
  gload_lds16(q + goA0, LAb(0) + loA0);
  gload_lds16(q + goA1, LAb(0) + loA1);
  gload_lds16(wt + goB0, LBb(0) + loB0);
  gload_lds16(wt + goB1, LBb(0) + loB1);
  gload_lds16(wt + goB2, LBb(0) + loB2);
  gload_lds16(wt + goB3, LBb(0) + loB3);
  gload_lds16(q + goA2, LAb(0) + loA2);
  gload_lds16(q + goA3, LAb(0) + loA3);
  asm volatile("s_waitcnt vmcnt(4)" ::: "memory");
  __builtin_amdgcn_s_barrier();

  for (int kt = 0; kt < NKT; ++kt) {
    const int cur = kt & 1;
    const signed char* lAc = LAb(cur);
    const signed char* lBc = LBb(cur);
    signed char* lAn = LAb(cur ^ 1);
    signed char* lBn = LBb(cur ^ 1);
    const unsigned kbn = (unsigned)(((kt + 1) & (NKT - 1)) * BK);

    // ---------- phase 0: read A(mh0)+B(nh0); issue A0,A1; MFMA q(0,0)
#pragma unroll
    for (int mi = 0; mi < 4; ++mi) {
      const int row = wm * 128 + mi * 16 + fl;
      af[mi][0] = *(const i32x4*)(lAc + row * BK + ps0 * 16);
      af[mi][1] = *(const i32x4*)(lAc + row * BK + ps1 * 16);
    }
#pragma unroll
    for (int ni = 0; ni < 2; ++ni) {
      const int row = wn * 64 + ni * 16 + fl;
      bf0[ni][0] = *(const i32x4*)(lBc + row * BK + ps0 * 16);
      bf0[ni][1] = *(const i32x4*)(lBc + row * BK + ps1 * 16);
    }
    gload_lds16(q + (goA0 + kbn), lAn + loA0);
    gload_lds16(q + (goA1 + kbn), lAn + loA1);
    asm volatile("s_waitcnt lgkmcnt(0)" ::: "memory");
    __builtin_amdgcn_sched_barrier(0);
    __builtin_amdgcn_s_setprio(1);
#pragma unroll
    for (int mi = 0; mi < 4; ++mi)
#pragma unroll
      for (int ni = 0; ni < 2; ++ni) {
        acc[mi][ni] = MFMA_I8(af[mi][0], bf0[ni][0], acc[mi][ni]);
        acc[mi][ni] = MFMA_I8(af[mi][1], bf0[ni][1], acc[mi][ni]);
      }
    __builtin_amdgcn_s_setprio(0);
    asm volatile("s_waitcnt vmcnt(2)" ::: "memory");
    __builtin_amdgcn_s_barrier();

    // ---------- phase 1: read B(nh1); issue B0,B1; MFMA q(0,1)
    //            (no vmcnt / no barrier at end: nothing published here)
#pragma unroll
    for (int ni = 0; ni < 2; ++ni) {
      const int row = wn * 64 + 32 + ni * 16 + fl;
      bf1[ni][0] = *(const i32x4*)(lBc + row * BK + ps0 * 16);
      bf1[ni][1] = *(const i32x4*)(lBc + row * BK + ps1 * 16);
    }
    gload_lds16(wt + (goB0 + kbn), lBn + loB0);
    gload_lds16(wt + (goB1 + kbn), lBn + loB1);
    asm volatile("s_waitcnt lgkmcnt(0)" ::: "memory");
    __builtin_amdgcn_sched_barrier(0);
    __builtin_amdgcn_s_setprio(1);
#pragma unroll
    for (int mi = 0; mi < 4; ++mi)
#pragma unroll
      for (int ni = 0; ni < 2; ++ni) {
        acc[mi][2 + ni] = MFMA_I8(af[mi][0], bf1[ni][0], acc[mi][2 + ni]);
        acc[mi][2 + ni] = MFMA_I8(af[mi][1], bf1[ni][1], acc[mi][2 + ni]);
      }
    __builtin_amdgcn_s_setprio(0);

    // ---------- phase 2 (merged): read A(mh1); issue B2,B3,A2,A3;
    //            MFMA q(1,1) then q(1,0) as one 32-MFMA cluster
#pragma unroll
    for (int mi = 0; mi < 4; ++mi) {
      const int row = wm * 128 + 64 + mi * 16 + fl;
      af[mi][0] = *(const i32x4*)(lAc + row * BK + ps0 * 16);
      af[mi][1] = *(const i32x4*)(lAc + row * BK + ps1 * 16);
    }
    gload_lds16(wt + (goB2 + kbn), lBn + loB2);
    gload_lds16(wt + (goB3 + kbn), lBn + loB3);
    gload_lds16(q + (goA2 + kbn), lAn + loA2);
    gload_lds16(q + (goA3 + kbn), lAn + loA3);
    asm volatile("s_waitcnt lgkmcnt(0)" ::: "memory");
    __builtin_amdgcn_sched_barrier(0);
    __builtin_amdgcn_s_setprio(1);
#pragma unroll
    for (int mi = 0; mi < 4; ++mi)
#pragma unroll
      for (int ni = 0; ni < 2; ++ni) {
        acc[4 + mi][2 + ni] = MFMA_I8(af[mi][0], bf1[ni][0], acc[4 + mi][2 + ni]);
        acc[4 + mi][2 + ni] = MFMA_I8(af[mi][1], bf1[ni][1], acc[4 + mi][2 + ni]);
      }
#pragma unroll
    for (int mi = 0; mi < 4; ++mi)
#pragma unroll
      for (int ni = 0; ni < 2; ++ni) {
        acc[4 + mi][ni] = MFMA_I8(af[mi][0], bf0[ni][0], acc[4 + mi][ni]);
        acc[4 + mi][ni] = MFMA_I8(af[mi][1], bf0[ni][1], acc[4 + mi][ni]);
      }
    __builtin_amdgcn_s_setprio(0);
    asm volatile("s_waitcnt vmcnt(4)" ::: "memory");
    __builtin_amdgcn_s_barrier();
  }

  // ---- epilogue: dequant -> LDS (row-major 128x256 f32) -> coalesced
  //      nt dwordx4 stores. Drain wrapped prefetch before LDS reuse.
  asm volatile("s_waitcnt vmcnt(0)" ::: "memory");
  __builtin_amdgcn_s_barrier();
  float* lout = reinterpret_cast<float*>(lsmem);

#pragma unroll
  for (int p = 0; p < 2; ++p) {
    if (p) __builtin_amdgcn_s_barrier();  // pass-0 reads done before rewrite
    if (wm == p) {
#pragma unroll
      for (int mi = 0; mi < 8; ++mi) {
        const int lrb = (mi >> 2) * 64 + (mi & 3) * 16 + fk * 4;  // 0..127
        const int grow = m0 + wm * 128 + lrb;
        float is4[4];
#pragma unroll
        for (int r = 0; r < 4; ++r) is4[r] = iscale[grow + r];
#pragma unroll
        for (int ni = 0; ni < 4; ++ni) {
          const int ccol = wn * 64 + (ni >> 1) * 32 + (ni & 1) * 16 + fl;
          const float wsc = wscale[n0 + ccol];
          const float bs = bias[n0 + ccol];
#pragma unroll
          for (int r = 0; r < 4; ++r)
            lout[(lrb + r) * 256 + ccol] =
                (float)acc[mi][ni][r] * is4[r] * wsc + bs;
        }
      }
    }
    __builtin_amdgcn_s_barrier();
#pragma unroll
    for (int j = 0; j < 16; ++j) {
      const int unit = t + j * 512;
      const int lr = unit >> 6;         // 0..127
      const int c4 = (unit & 63) << 2;  // float col, 4-aligned
      f32x4 v = *reinterpret_cast<const f32x4*>(&lout[lr * 256 + c4]);
      __builtin_nontemporal_store(
          v, reinterpret_cast<f32x4*>(
                 &out[(size_t)(m0 + p * 128 + lr) * N_DIM + n0 + c4]));
    }
  }
#undef LAb
#undef LBb
}

extern "C" void kernel_launch(void* const* d_in, const int* in_sizes, int n_in,
                              void* d_out, int out_size, void* d_ws, size_t ws_size,
                              hipStream_t stream) {
  const float* inp = (const float*)d_in[0];
  const int* wq32 = (const int*)d_in[1];  // int8 weight delivered as int32 [K][N]
  const float* wscale = (const float*)d_in[2];
  const float* bias = (const float*)d_in[3];
  float* out = (float*)d_out;

  signed char* q = (signed char*)d_ws;
  signed char* wt = q + (size_t)M_DIM * K_DIM;
  float* iscale = (float*)(wt + (size_t)N_DIM * K_DIM);

  // fused quant (8192 blocks) + transpose (4096 blocks) in one launch
  prep_fused<<<M_DIM + (N_DIM / 64) * (K_DIM / 64), 256, 0, stream>>>(
      inp, q, iscale, wq32, wt);
  gemm_i8<<<dim3(N_DIM / BN, M_DIM / BM), 512, 0, stream>>>(q, wt, iscale, wscale,
                                                            bias, out);
}